// Round 3
// baseline (919.932 us; speedup 1.0000x reference)
//
#include <hip/hip_runtime.h>
#include <math.h>

#define TT 4096
#define DD 1024
#define EE 8
#define HH 4096
#define NEXP 9   // 8 routed experts + shared expert as index 8

typedef __bf16 bf16;
typedef __bf16 bf16x8 __attribute__((ext_vector_type(8)));
typedef float  f32x4  __attribute__((ext_vector_type(4)));

// async global->LDS, 16B per lane; LDS dest is wave-uniform base + lane*16
#define GLOAD_LDS16(gptr, lptr)                                                   \
  __builtin_amdgcn_global_load_lds(                                               \
      (const __attribute__((address_space(1))) void*)(gptr),                      \
      (__attribute__((address_space(3))) void*)(lptr), 16, 0, 0)

// ---------------- init: zero out + counters, convert x -> bf16 ----------------
__global__ void k_init(const float* __restrict__ x, bf16* __restrict__ xb,
                       float* __restrict__ out, int* __restrict__ counts,
                       int* __restrict__ cursors) {
  int i = blockIdx.x * blockDim.x + threadIdx.x;
  if (i < TT * DD) { xb[i] = (bf16)x[i]; out[i] = 0.0f; }
  if (i < EE) { counts[i] = 0; cursors[i] = 0; }
}

// ---------------- routing: one wave per token ----------------
__global__ void k_route(const float* __restrict__ x, const float* __restrict__ gw,
                        const float* __restrict__ gb, const float* __restrict__ rb,
                        int* __restrict__ counts, int* __restrict__ tke,
                        float* __restrict__ tkp) {
  int gid = blockIdx.x * blockDim.x + threadIdx.x;
  int t = gid >> 6;
  int lane = gid & 63;
  if (t >= TT) return;
  const float* xt = x + (size_t)t * DD;
  float acc[EE];
#pragma unroll
  for (int e = 0; e < EE; e++) acc[e] = 0.f;
  for (int d = lane; d < DD; d += 64) {
    float xv = xt[d];
    const float* g = gw + (size_t)d * EE;
#pragma unroll
    for (int e = 0; e < EE; e++) acc[e] += xv * g[e];
  }
#pragma unroll
  for (int off = 32; off > 0; off >>= 1) {
#pragma unroll
    for (int e = 0; e < EE; e++) acc[e] += __shfl_down(acc[e], off);
  }
  if (lane == 0) {
    float l[EE];
#pragma unroll
    for (int e = 0; e < EE; e++) l[e] = acc[e] + gb[e] + rb[e];
    int i1 = 0;
#pragma unroll
    for (int e = 1; e < EE; e++) if (l[e] > l[i1]) i1 = e;
    int i2 = (i1 == 0) ? 1 : 0;
#pragma unroll
    for (int e = 0; e < EE; e++) if (e != i1 && l[e] > l[i2]) i2 = e;
    float e2 = expf(l[i2] - l[i1]);
    float s = 1.f + e2;
    tke[t * 2 + 0] = i1; tkp[t * 2 + 0] = 1.f / s;
    tke[t * 2 + 1] = i2; tkp[t * 2 + 1] = e2 / s;
    atomicAdd(&counts[i1], 1);
    atomicAdd(&counts[i2], 1);
  }
}

// ---------------- prefix: expert row bases ----------------
__global__ void k_prefix(const int* __restrict__ counts, int* __restrict__ expBase,
                         int* __restrict__ expCnt) {
  if (blockIdx.x == 0 && threadIdx.x == 0) {
    int off = TT;  // rows [0, TT) are the shared expert
    for (int e = 0; e < EE; e++) { expBase[e] = off; expCnt[e] = counts[e]; off += counts[e]; }
    expBase[8] = 0; expCnt[8] = TT;
  }
}

// ---------------- scatter: fill packed row lists ----------------
__global__ void k_scatter(const int* __restrict__ tke, const float* __restrict__ tkp,
                          const int* __restrict__ expBase, int* __restrict__ cursors,
                          int* __restrict__ rowTok, float* __restrict__ rowW) {
  int t = blockIdx.x * blockDim.x + threadIdx.x;
  if (t >= TT) return;
  rowTok[t] = t; rowW[t] = 1.f;
#pragma unroll
  for (int k = 0; k < 2; k++) {
    int e = tke[t * 2 + k];
    float p = tkp[t * 2 + k];
    int slot = atomicAdd(&cursors[e], 1);
    int r = expBase[e] + slot;
    rowTok[r] = t; rowW[r] = p;
  }
}

// ---------------- weight transpose+convert: W[K][N] fp32 -> Wt[N][K] bf16 ----------------
// 64x64 tile; reads 64B/quad contiguous; writes 16B/lane bf16x8, quad-contiguous.
// grid: (N/64, K/64, 9); z=8 -> shared, else expert z
__global__ __launch_bounds__(256) void k_wt(const float* __restrict__ expW,
                                            const float* __restrict__ shW,
                                            bf16* __restrict__ outT, int K, int N) {
  __shared__ float t[64][65];   // pad 65: column reads are 2-way (free)
  int z = blockIdx.z;
  const float* W = (z == 8) ? shW : expW + (size_t)z * K * N;
  bf16* O = outT + (size_t)z * K * N;
  int n0 = blockIdx.x * 64, k0 = blockIdx.y * 64;
  int tid = threadIdx.x;
  int kr = tid >> 2;            // 0..63
  int cf = (tid & 3) * 16;      // 0,16,32,48
#pragma unroll
  for (int i = 0; i < 4; i++) {
    f32x4 v = *(const f32x4*)&W[(size_t)(k0 + kr) * N + n0 + cf + i * 4];
    t[kr][cf + i * 4 + 0] = v[0];
    t[kr][cf + i * 4 + 1] = v[1];
    t[kr][cf + i * 4 + 2] = v[2];
    t[kr][cf + i * 4 + 3] = v[3];
  }
  __syncthreads();
  int nr = tid >> 2;            // 0..63
  int kf = (tid & 3) * 16;
  bf16x8 o0, o1;
#pragma unroll
  for (int j = 0; j < 8; j++) o0[j] = (bf16)t[kf + j][nr];
#pragma unroll
  for (int j = 0; j < 8; j++) o1[j] = (bf16)t[kf + 8 + j][nr];
  bf16* dst = O + (size_t)(n0 + nr) * K + k0 + kf;
  *(bf16x8*)dst = o0;
  *(bf16x8*)(dst + 8) = o1;
}

// ---------------- grouped GEMM1: h = gelu(X @ W1 + b1), packed rows ----------------
__global__ __launch_bounds__(256, 2) void k_gemm1(
    const bf16* __restrict__ xb, const bf16* __restrict__ wt1,
    const float* __restrict__ sb1, const float* __restrict__ eb1,
    const int* __restrict__ rowTok, const int* __restrict__ expBase,
    const int* __restrict__ expCnt, bf16* __restrict__ hbuf) {
  int ex = blockIdx.z;
  int base = expBase[ex];
  int cnt  = expCnt[ex];
  int mt = blockIdx.y;
  if (mt * 128 >= cnt) return;
  int n0 = blockIdx.x * 128;
  const bf16* Bt = wt1 + (size_t)ex * HH * DD;   // [H][D] bf16
  const float* b1 = (ex == 8) ? sb1 : eb1 + (size_t)ex * HH;

  __shared__ bf16 As[128 * 32];
  __shared__ bf16 Bs[128 * 32];
  __shared__ int  toks[128];

  int tid = threadIdx.x;
  int lane = tid & 63;
  int wv = tid >> 6;
  int wm = (wv & 1) * 64;
  int wn = (wv >> 1) * 64;

  if (tid < 128) {
    int rr = min(mt * 128 + tid, cnt - 1);
    toks[tid] = rowTok[base + rr];
  }

  f32x4 acc[4][4];
#pragma unroll
  for (int a = 0; a < 4; a++)
#pragma unroll
    for (int b = 0; b < 4; b++) acc[a][b] = (f32x4){0.f, 0.f, 0.f, 0.f};

  __syncthreads();

  int r0 = wv * 32 + (lane >> 2);
  int c8 = (lane & 3) * 8;

  for (int k0 = 0; k0 < DD; k0 += 32) {
    GLOAD_LDS16(xb + (size_t)toks[r0] * DD + k0 + c8,      As + wv * 1024);
    GLOAD_LDS16(xb + (size_t)toks[r0 + 16] * DD + k0 + c8, As + wv * 1024 + 512);
    GLOAD_LDS16(Bt + (size_t)(n0 + r0) * DD + k0 + c8,      Bs + wv * 1024);
    GLOAD_LDS16(Bt + (size_t)(n0 + r0 + 16) * DD + k0 + c8, Bs + wv * 1024 + 512);
    __syncthreads();
    bf16x8 af[4], bfr[4];
#pragma unroll
    for (int mi = 0; mi < 4; mi++)
      af[mi] = *(const bf16x8*)&As[(wm + mi * 16 + (lane & 15)) * 32 + (lane >> 4) * 8];
#pragma unroll
    for (int ni = 0; ni < 4; ni++)
      bfr[ni] = *(const bf16x8*)&Bs[(wn + ni * 16 + (lane & 15)) * 32 + (lane >> 4) * 8];
#pragma unroll
    for (int mi = 0; mi < 4; mi++)
#pragma unroll
      for (int ni = 0; ni < 4; ni++)
        acc[mi][ni] = __builtin_amdgcn_mfma_f32_16x16x32_bf16(af[mi], bfr[ni], acc[mi][ni], 0, 0, 0);
    __syncthreads();
  }

  int rsub = (lane >> 4) * 4;
#pragma unroll
  for (int ni = 0; ni < 4; ni++) {
    int col = n0 + wn + ni * 16 + (lane & 15);
    float bias = b1[col];
#pragma unroll
    for (int mi = 0; mi < 4; mi++) {
#pragma unroll
      for (int r = 0; r < 4; r++) {
        int mrow = mt * 128 + wm + mi * 16 + rsub + r;
        if (mrow < cnt) {
          float v = acc[mi][ni][r] + bias;
          v = 0.5f * v * (1.f + erff(v * 0.70710678118654752f));
          hbuf[(size_t)(base + mrow) * HH + col] = (bf16)v;
        }
      }
    }
  }
}

// ---------------- grouped GEMM2 (split-K x2): out += rowW * (h @ W2 + b2) ----------------
__global__ __launch_bounds__(256, 2) void k_gemm2(
    const bf16* __restrict__ hbuf, const bf16* __restrict__ wt2,
    const float* __restrict__ sb2, const float* __restrict__ eb2,
    const int* __restrict__ rowTok, const float* __restrict__ rowW,
    const int* __restrict__ expBase, const int* __restrict__ expCnt,
    float* __restrict__ out) {
  int ex = blockIdx.z;
  int base = expBase[ex];
  int cnt  = expCnt[ex];
  int ks = blockIdx.y & 1;        // split-K half
  int mt = blockIdx.y >> 1;
  if (mt * 128 >= cnt) return;
  int n0 = blockIdx.x * 128;
  const bf16* Bt = wt2 + (size_t)ex * DD * HH;   // [D][H] bf16
  const float* b2 = (ex == 8) ? sb2 : eb2 + (size_t)ex * DD;

  __shared__ bf16 As[128 * 32];
  __shared__ bf16 Bs[128 * 32];
  __shared__ int   toks[128];
  __shared__ float wrow[128];

  int tid = threadIdx.x;
  int lane = tid & 63;
  int wv = tid >> 6;
  int wm = (wv & 1) * 64;
  int wn = (wv >> 1) * 64;

  if (tid < 128) {
    int rr = min(mt * 128 + tid, cnt - 1);
    toks[tid] = rowTok[base + rr];
    wrow[tid] = rowW[base + rr];
  }

  f32x4 acc[4][4];
#pragma unroll
  for (int a = 0; a < 4; a++)
#pragma unroll
    for (int b = 0; b < 4; b++) acc[a][b] = (f32x4){0.f, 0.f, 0.f, 0.f};

  __syncthreads();

  int r0 = wv * 32 + (lane >> 2);
  int c8 = (lane & 3) * 8;
  int pr0 = base + min(mt * 128 + r0, cnt - 1);
  int pr1 = base + min(mt * 128 + r0 + 16, cnt - 1);
  const bf16* ga0 = hbuf + (size_t)pr0 * HH + c8;
  const bf16* ga1 = hbuf + (size_t)pr1 * HH + c8;

  int kbeg = ks * (HH / 2), kend = kbeg + (HH / 2);
  for (int k0 = kbeg; k0 < kend; k0 += 32) {
    GLOAD_LDS16(ga0 + k0, As + wv * 1024);
    GLOAD_LDS16(ga1 + k0, As + wv * 1024 + 512);
    GLOAD_LDS16(Bt + (size_t)(n0 + r0) * HH + k0 + c8,      Bs + wv * 1024);
    GLOAD_LDS16(Bt + (size_t)(n0 + r0 + 16) * HH + k0 + c8, Bs + wv * 1024 + 512);
    __syncthreads();
    bf16x8 af[4], bfr[4];
#pragma unroll
    for (int mi = 0; mi < 4; mi++)
      af[mi] = *(const bf16x8*)&As[(wm + mi * 16 + (lane & 15)) * 32 + (lane >> 4) * 8];
#pragma unroll
    for (int ni = 0; ni < 4; ni++)
      bfr[ni] = *(const bf16x8*)&Bs[(wn + ni * 16 + (lane & 15)) * 32 + (lane >> 4) * 8];
#pragma unroll
    for (int mi = 0; mi < 4; mi++)
#pragma unroll
      for (int ni = 0; ni < 4; ni++)
        acc[mi][ni] = __builtin_amdgcn_mfma_f32_16x16x32_bf16(af[mi], bfr[ni], acc[mi][ni], 0, 0, 0);
    __syncthreads();
  }

  int rsub = (lane >> 4) * 4;
#pragma unroll
  for (int ni = 0; ni < 4; ni++) {
    int col = n0 + wn + ni * 16 + (lane & 15);
    float bias = (ks == 0) ? b2[col] : 0.f;   // bias added exactly once per output
#pragma unroll
    for (int mi = 0; mi < 4; mi++) {
#pragma unroll
      for (int r = 0; r < 4; r++) {
        int local = wm + mi * 16 + rsub + r;
        int mrow = mt * 128 + local;
        if (mrow < cnt) {
          float v = acc[mi][ni][r] + bias;
          atomicAdd(&out[(size_t)toks[local] * DD + col], wrow[local] * v);
        }
      }
    }
  }
}

extern "C" void kernel_launch(void* const* d_in, const int* in_sizes, int n_in,
                              void* d_out, int out_size, void* d_ws, size_t ws_size,
                              hipStream_t stream) {
  const float* x   = (const float*)d_in[0];
  const float* gw  = (const float*)d_in[1];
  const float* gb  = (const float*)d_in[2];
  const float* rb  = (const float*)d_in[3];
  const float* sw1 = (const float*)d_in[4];
  const float* sb1 = (const float*)d_in[5];
  const float* sw2 = (const float*)d_in[6];
  const float* sb2 = (const float*)d_in[7];
  const float* ew1 = (const float*)d_in[8];
  const float* eb1 = (const float*)d_in[9];
  const float* ew2 = (const float*)d_in[10];
  const float* eb2 = (const float*)d_in[11];
  float* out = (float*)d_out;

  char* p = (char*)d_ws;
  bf16* xb    = (bf16*)p;  p += (size_t)TT * DD * sizeof(bf16);          // 8 MB
  bf16* hbuf  = (bf16*)p;  p += (size_t)(3 * TT) * HH * sizeof(bf16);    // 96 MB
  bf16* wtb   = (bf16*)p;  p += (size_t)NEXP * DD * HH * sizeof(bf16);   // 75.5 MB (W1^T, then W2^T)
  int* rowTok = (int*)p;   p += (size_t)(3 * TT) * sizeof(int);
  float* rowW = (float*)p; p += (size_t)(3 * TT) * sizeof(float);
  int* tke    = (int*)p;   p += (size_t)TT * 2 * sizeof(int);
  float* tkp  = (float*)p; p += (size_t)TT * 2 * sizeof(float);
  int* counts = (int*)p;   p += EE * sizeof(int);
  int* cursors= (int*)p;   p += EE * sizeof(int);
  int* expBase= (int*)p;   p += NEXP * sizeof(int);
  int* expCnt = (int*)p;   p += NEXP * sizeof(int);

  k_init<<<(TT * DD + 255) / 256, 256, 0, stream>>>(x, xb, out, counts, cursors);
  k_route<<<TT / 4, 256, 0, stream>>>(x, gw, gb, rb, counts, tke, tkp);
  k_prefix<<<1, 64, 0, stream>>>(counts, expBase, expCnt);
  k_scatter<<<TT / 256, 256, 0, stream>>>(tke, tkp, expBase, cursors, rowTok, rowW);

  // W1^T: [DD][HH] fp32 -> [HH][DD] bf16
  dim3 gt1(HH / 64, DD / 64, NEXP);
  k_wt<<<gt1, 256, 0, stream>>>(ew1, sw1, wtb, DD, HH);
  dim3 g1(HH / 128, 32, NEXP);
  k_gemm1<<<g1, 256, 0, stream>>>(xb, wtb, sb1, eb1, rowTok, expBase, expCnt, hbuf);

  // W2^T: [HH][DD] fp32 -> [DD][HH] bf16 (overwrites W1^T)
  dim3 gt2(DD / 64, HH / 64, NEXP);
  k_wt<<<gt2, 256, 0, stream>>>(ew2, sw2, wtb, HH, DD);
  dim3 g2(DD / 128, 64, NEXP);   // y = mt*2 + ks (split-K x2)
  k_gemm2<<<g2, 256, 0, stream>>>(hbuf, wtb, sb2, eb2, rowTok, rowW, expBase, expCnt, out);
}

// Round 4
// 904.472 us; speedup vs baseline: 1.0171x; 1.0171x over previous
//
#include <hip/hip_runtime.h>
#include <math.h>

#define TT 4096
#define DD 1024
#define EE 8
#define HH 4096
#define NEXP 9     // 8 routed experts + shared expert as index 8
#define NTMAX 104  // worst-case total m-tiles: 32 shared + 64+7 experts
#define NSG 13     // ceil(NTMAX/8) supergroups

typedef __bf16 bf16;
typedef __bf16 bf16x8 __attribute__((ext_vector_type(8)));
typedef float  f32x4  __attribute__((ext_vector_type(4)));

// async global->LDS, 16B per lane; LDS dest is wave-uniform base + lane*16
#define GLOAD_LDS16(gptr, lptr)                                                   \
  __builtin_amdgcn_global_load_lds(                                               \
      (const __attribute__((address_space(1))) void*)(gptr),                      \
      (__attribute__((address_space(3))) void*)(lptr), 16, 0, 0)

// ---------------- init: zero out + counters, convert x -> bf16 ----------------
__global__ void k_init(const float* __restrict__ x, bf16* __restrict__ xb,
                       float* __restrict__ out, int* __restrict__ counts,
                       int* __restrict__ cursors) {
  int i = blockIdx.x * blockDim.x + threadIdx.x;
  if (i < TT * DD) { xb[i] = (bf16)x[i]; out[i] = 0.0f; }
  if (i < EE) { counts[i] = 0; cursors[i] = 0; }
}

// ---------------- routing: one wave per token ----------------
__global__ void k_route(const float* __restrict__ x, const float* __restrict__ gw,
                        const float* __restrict__ gb, const float* __restrict__ rb,
                        int* __restrict__ counts, int* __restrict__ tke,
                        float* __restrict__ tkp) {
  int gid = blockIdx.x * blockDim.x + threadIdx.x;
  int t = gid >> 6;
  int lane = gid & 63;
  if (t >= TT) return;
  const float* xt = x + (size_t)t * DD;
  float acc[EE];
#pragma unroll
  for (int e = 0; e < EE; e++) acc[e] = 0.f;
  for (int d = lane; d < DD; d += 64) {
    float xv = xt[d];
    const float* g = gw + (size_t)d * EE;
#pragma unroll
    for (int e = 0; e < EE; e++) acc[e] += xv * g[e];
  }
#pragma unroll
  for (int off = 32; off > 0; off >>= 1) {
#pragma unroll
    for (int e = 0; e < EE; e++) acc[e] += __shfl_down(acc[e], off);
  }
  if (lane == 0) {
    float l[EE];
#pragma unroll
    for (int e = 0; e < EE; e++) l[e] = acc[e] + gb[e] + rb[e];
    int i1 = 0;
#pragma unroll
    for (int e = 1; e < EE; e++) if (l[e] > l[i1]) i1 = e;
    int i2 = (i1 == 0) ? 1 : 0;
#pragma unroll
    for (int e = 0; e < EE; e++) if (e != i1 && l[e] > l[i2]) i2 = e;
    float e2 = expf(l[i2] - l[i1]);
    float s = 1.f + e2;
    tke[t * 2 + 0] = i1; tkp[t * 2 + 0] = 1.f / s;
    tke[t * 2 + 1] = i2; tkp[t * 2 + 1] = e2 / s;
    atomicAdd(&counts[i1], 1);
    atomicAdd(&counts[i2], 1);
  }
}

// ---------------- prefix: expert row bases + flattened tile table ----------------
__global__ void k_prefix(const int* __restrict__ counts, int* __restrict__ expBase,
                         int* __restrict__ expCnt, int* __restrict__ tileExp,
                         int* __restrict__ tileM, int* __restrict__ nTiles) {
  if (blockIdx.x == 0 && threadIdx.x == 0) {
    int off = TT;  // rows [0, TT) are the shared expert
    for (int e = 0; e < EE; e++) { expBase[e] = off; expCnt[e] = counts[e]; off += counts[e]; }
    expBase[8] = 0; expCnt[8] = TT;
    int idx = 0;
    for (int mt = 0; mt < TT / 128; mt++) { tileExp[idx] = 8; tileM[idx] = mt; idx++; }
    for (int e = 0; e < EE; e++) {
      int nt = (counts[e] + 127) >> 7;
      for (int mt = 0; mt < nt; mt++) { tileExp[idx] = e; tileM[idx] = mt; idx++; }
    }
    *nTiles = idx;
  }
}

// ---------------- scatter: fill packed row lists ----------------
__global__ void k_scatter(const int* __restrict__ tke, const float* __restrict__ tkp,
                          const int* __restrict__ expBase, int* __restrict__ cursors,
                          int* __restrict__ rowTok, float* __restrict__ rowW) {
  int t = blockIdx.x * blockDim.x + threadIdx.x;
  if (t >= TT) return;
  rowTok[t] = t; rowW[t] = 1.f;
#pragma unroll
  for (int k = 0; k < 2; k++) {
    int e = tke[t * 2 + k];
    float p = tkp[t * 2 + k];
    int slot = atomicAdd(&cursors[e], 1);
    int r = expBase[e] + slot;
    rowTok[r] = t; rowW[r] = p;
  }
}

// ---------------- weight transpose+convert: W[K][N] fp32 -> Wt[N][K] bf16 ----------------
__global__ __launch_bounds__(256) void k_wt(const float* __restrict__ expW,
                                            const float* __restrict__ shW,
                                            bf16* __restrict__ outT, int K, int N) {
  __shared__ float t[64][65];
  int z = blockIdx.z;
  const float* W = (z == 8) ? shW : expW + (size_t)z * K * N;
  bf16* O = outT + (size_t)z * K * N;
  int n0 = blockIdx.x * 64, k0 = blockIdx.y * 64;
  int tid = threadIdx.x;
  int kr = tid >> 2;
  int cf = (tid & 3) * 16;
#pragma unroll
  for (int i = 0; i < 4; i++) {
    f32x4 v = *(const f32x4*)&W[(size_t)(k0 + kr) * N + n0 + cf + i * 4];
    t[kr][cf + i * 4 + 0] = v[0];
    t[kr][cf + i * 4 + 1] = v[1];
    t[kr][cf + i * 4 + 2] = v[2];
    t[kr][cf + i * 4 + 3] = v[3];
  }
  __syncthreads();
  int nr = tid >> 2;
  int kf = (tid & 3) * 16;
  bf16x8 o0, o1;
#pragma unroll
  for (int j = 0; j < 8; j++) o0[j] = (bf16)t[kf + j][nr];
#pragma unroll
  for (int j = 0; j < 8; j++) o1[j] = (bf16)t[kf + 8 + j][nr];
  bf16* dst = O + (size_t)(n0 + nr) * K + k0 + kf;
  *(bf16x8*)dst = o0;
  *(bf16x8*)(dst + 8) = o1;
}

// ---------------- grouped GEMM1: h = gelu(X @ W1 + b1), swizzled flat grid ----------------
// bid decode: 8 consecutive blocks share one B panel (-> 8 XCDs, 1 LLC fetch);
// bid+8 (same XCD) reuses the same A panel from its L2 across the n-sweep.
__global__ __launch_bounds__(256, 2) void k_gemm1(
    const bf16* __restrict__ xb, const bf16* __restrict__ wt1,
    const float* __restrict__ sb1, const float* __restrict__ eb1,
    const int* __restrict__ rowTok, const int* __restrict__ expBase,
    const int* __restrict__ expCnt, const int* __restrict__ tileExp,
    const int* __restrict__ tileM, const int* __restrict__ nTiles,
    bf16* __restrict__ hbuf) {
  int bid = blockIdx.x;
  int sg  = bid >> 8;           // / (8 groups * 32 n-tiles)
  int rem = bid & 255;
  int n   = rem >> 3;
  int dm  = rem & 7;
  int tIdx = sg * 8 + dm;
  if (tIdx >= *nTiles) return;
  int ex = tileExp[tIdx];
  int mt = tileM[tIdx];
  int base = expBase[ex];
  int cnt  = expCnt[ex];
  int n0 = n * 128;
  const bf16* Bt = wt1 + (size_t)ex * HH * DD;   // [H][D] bf16
  const float* b1 = (ex == 8) ? sb1 : eb1 + (size_t)ex * HH;

  __shared__ bf16 As[128 * 32];
  __shared__ bf16 Bs[128 * 32];
  __shared__ int  toks[128];

  int tid = threadIdx.x;
  int lane = tid & 63;
  int wv = tid >> 6;
  int wm = (wv & 1) * 64;
  int wn = (wv >> 1) * 64;

  if (tid < 128) {
    int rr = min(mt * 128 + tid, cnt - 1);
    toks[tid] = rowTok[base + rr];
  }

  f32x4 acc[4][4];
#pragma unroll
  for (int a = 0; a < 4; a++)
#pragma unroll
    for (int b = 0; b < 4; b++) acc[a][b] = (f32x4){0.f, 0.f, 0.f, 0.f};

  __syncthreads();

  int r0 = wv * 32 + (lane >> 2);
  int c8 = (lane & 3) * 8;

  for (int k0 = 0; k0 < DD; k0 += 32) {
    GLOAD_LDS16(xb + (size_t)toks[r0] * DD + k0 + c8,      As + wv * 1024);
    GLOAD_LDS16(xb + (size_t)toks[r0 + 16] * DD + k0 + c8, As + wv * 1024 + 512);
    GLOAD_LDS16(Bt + (size_t)(n0 + r0) * DD + k0 + c8,      Bs + wv * 1024);
    GLOAD_LDS16(Bt + (size_t)(n0 + r0 + 16) * DD + k0 + c8, Bs + wv * 1024 + 512);
    __syncthreads();
    bf16x8 af[4], bfr[4];
#pragma unroll
    for (int mi = 0; mi < 4; mi++)
      af[mi] = *(const bf16x8*)&As[(wm + mi * 16 + (lane & 15)) * 32 + (lane >> 4) * 8];
#pragma unroll
    for (int ni = 0; ni < 4; ni++)
      bfr[ni] = *(const bf16x8*)&Bs[(wn + ni * 16 + (lane & 15)) * 32 + (lane >> 4) * 8];
#pragma unroll
    for (int mi = 0; mi < 4; mi++)
#pragma unroll
      for (int ni = 0; ni < 4; ni++)
        acc[mi][ni] = __builtin_amdgcn_mfma_f32_16x16x32_bf16(af[mi], bfr[ni], acc[mi][ni], 0, 0, 0);
    __syncthreads();
  }

  int rsub = (lane >> 4) * 4;
#pragma unroll
  for (int ni = 0; ni < 4; ni++) {
    int col = n0 + wn + ni * 16 + (lane & 15);
    float bias = b1[col];
#pragma unroll
    for (int mi = 0; mi < 4; mi++) {
#pragma unroll
      for (int r = 0; r < 4; r++) {
        int mrow = mt * 128 + wm + mi * 16 + rsub + r;
        if (mrow < cnt) {
          float v = acc[mi][ni][r] + bias;
          v = 0.5f * v * (1.f + erff(v * 0.70710678118654752f));
          hbuf[(size_t)(base + mrow) * HH + col] = (bf16)v;
        }
      }
    }
  }
}

// ---------------- grouped GEMM2: out += rowW * (h @ W2 + b2), swizzled flat grid ----------------
__global__ __launch_bounds__(256, 2) void k_gemm2(
    const bf16* __restrict__ hbuf, const bf16* __restrict__ wt2,
    const float* __restrict__ sb2, const float* __restrict__ eb2,
    const int* __restrict__ rowTok, const float* __restrict__ rowW,
    const int* __restrict__ expBase, const int* __restrict__ expCnt,
    const int* __restrict__ tileExp, const int* __restrict__ tileM,
    const int* __restrict__ nTiles, float* __restrict__ out) {
  int bid = blockIdx.x;
  int sg  = bid >> 6;           // / (8 groups * 8 n-tiles)
  int rem = bid & 63;
  int n   = rem >> 3;
  int dm  = rem & 7;
  int tIdx = sg * 8 + dm;
  if (tIdx >= *nTiles) return;
  int ex = tileExp[tIdx];
  int mt = tileM[tIdx];
  int base = expBase[ex];
  int cnt  = expCnt[ex];
  int n0 = n * 128;
  const bf16* Bt = wt2 + (size_t)ex * DD * HH;   // [D][H] bf16
  const float* b2 = (ex == 8) ? sb2 : eb2 + (size_t)ex * DD;

  __shared__ bf16 As[128 * 32];
  __shared__ bf16 Bs[128 * 32];
  __shared__ int   toks[128];
  __shared__ float wrow[128];

  int tid = threadIdx.x;
  int lane = tid & 63;
  int wv = tid >> 6;
  int wm = (wv & 1) * 64;
  int wn = (wv >> 1) * 64;

  if (tid < 128) {
    int rr = min(mt * 128 + tid, cnt - 1);
    toks[tid] = rowTok[base + rr];
    wrow[tid] = rowW[base + rr];
  }

  f32x4 acc[4][4];
#pragma unroll
  for (int a = 0; a < 4; a++)
#pragma unroll
    for (int b = 0; b < 4; b++) acc[a][b] = (f32x4){0.f, 0.f, 0.f, 0.f};

  __syncthreads();

  int r0 = wv * 32 + (lane >> 2);
  int c8 = (lane & 3) * 8;
  int pr0 = base + min(mt * 128 + r0, cnt - 1);
  int pr1 = base + min(mt * 128 + r0 + 16, cnt - 1);
  const bf16* ga0 = hbuf + (size_t)pr0 * HH + c8;
  const bf16* ga1 = hbuf + (size_t)pr1 * HH + c8;

  for (int k0 = 0; k0 < HH; k0 += 32) {
    GLOAD_LDS16(ga0 + k0, As + wv * 1024);
    GLOAD_LDS16(ga1 + k0, As + wv * 1024 + 512);
    GLOAD_LDS16(Bt + (size_t)(n0 + r0) * HH + k0 + c8,      Bs + wv * 1024);
    GLOAD_LDS16(Bt + (size_t)(n0 + r0 + 16) * HH + k0 + c8, Bs + wv * 1024 + 512);
    __syncthreads();
    bf16x8 af[4], bfr[4];
#pragma unroll
    for (int mi = 0; mi < 4; mi++)
      af[mi] = *(const bf16x8*)&As[(wm + mi * 16 + (lane & 15)) * 32 + (lane >> 4) * 8];
#pragma unroll
    for (int ni = 0; ni < 4; ni++)
      bfr[ni] = *(const bf16x8*)&Bs[(wn + ni * 16 + (lane & 15)) * 32 + (lane >> 4) * 8];
#pragma unroll
    for (int mi = 0; mi < 4; mi++)
#pragma unroll
      for (int ni = 0; ni < 4; ni++)
        acc[mi][ni] = __builtin_amdgcn_mfma_f32_16x16x32_bf16(af[mi], bfr[ni], acc[mi][ni], 0, 0, 0);
    __syncthreads();
  }

  int rsub = (lane >> 4) * 4;
#pragma unroll
  for (int ni = 0; ni < 4; ni++) {
    int col = n0 + wn + ni * 16 + (lane & 15);
    float bias = b2[col];
#pragma unroll
    for (int mi = 0; mi < 4; mi++) {
#pragma unroll
      for (int r = 0; r < 4; r++) {
        int local = wm + mi * 16 + rsub + r;
        int mrow = mt * 128 + local;
        if (mrow < cnt) {
          float v = acc[mi][ni][r] + bias;
          atomicAdd(&out[(size_t)toks[local] * DD + col], wrow[local] * v);
        }
      }
    }
  }
}

extern "C" void kernel_launch(void* const* d_in, const int* in_sizes, int n_in,
                              void* d_out, int out_size, void* d_ws, size_t ws_size,
                              hipStream_t stream) {
  const float* x   = (const float*)d_in[0];
  const float* gw  = (const float*)d_in[1];
  const float* gb  = (const float*)d_in[2];
  const float* rb  = (const float*)d_in[3];
  const float* sw1 = (const float*)d_in[4];
  const float* sb1 = (const float*)d_in[5];
  const float* sw2 = (const float*)d_in[6];
  const float* sb2 = (const float*)d_in[7];
  const float* ew1 = (const float*)d_in[8];
  const float* eb1 = (const float*)d_in[9];
  const float* ew2 = (const float*)d_in[10];
  const float* eb2 = (const float*)d_in[11];
  float* out = (float*)d_out;

  char* p = (char*)d_ws;
  bf16* xb    = (bf16*)p;  p += (size_t)TT * DD * sizeof(bf16);          // 8 MB
  bf16* hbuf  = (bf16*)p;  p += (size_t)(3 * TT) * HH * sizeof(bf16);    // 96 MB
  bf16* wtb   = (bf16*)p;  p += (size_t)NEXP * DD * HH * sizeof(bf16);   // 75.5 MB (W1^T, then W2^T)
  int* rowTok = (int*)p;   p += (size_t)(3 * TT) * sizeof(int);
  float* rowW = (float*)p; p += (size_t)(3 * TT) * sizeof(float);
  int* tke    = (int*)p;   p += (size_t)TT * 2 * sizeof(int);
  float* tkp  = (float*)p; p += (size_t)TT * 2 * sizeof(float);
  int* counts = (int*)p;   p += EE * sizeof(int);
  int* cursors= (int*)p;   p += EE * sizeof(int);
  int* expBase= (int*)p;   p += NEXP * sizeof(int);
  int* expCnt = (int*)p;   p += NEXP * sizeof(int);
  int* tileExp= (int*)p;   p += 128 * sizeof(int);
  int* tileM  = (int*)p;   p += 128 * sizeof(int);
  int* nTiles = (int*)p;   p += 8 * sizeof(int);

  k_init<<<(TT * DD + 255) / 256, 256, 0, stream>>>(x, xb, out, counts, cursors);
  k_route<<<TT / 4, 256, 0, stream>>>(x, gw, gb, rb, counts, tke, tkp);
  k_prefix<<<1, 64, 0, stream>>>(counts, expBase, expCnt, tileExp, tileM, nTiles);
  k_scatter<<<TT / 256, 256, 0, stream>>>(tke, tkp, expBase, cursors, rowTok, rowW);

  // W1^T: [DD][HH] fp32 -> [HH][DD] bf16
  dim3 gt1(HH / 64, DD / 64, NEXP);
  k_wt<<<gt1, 256, 0, stream>>>(ew1, sw1, wtb, DD, HH);
  k_gemm1<<<NSG * 8 * (HH / 128), 256, 0, stream>>>(xb, wtb, sb1, eb1, rowTok, expBase,
                                                    expCnt, tileExp, tileM, nTiles, hbuf);

  // W2^T: [HH][DD] fp32 -> [DD][HH] bf16 (overwrites W1^T)
  dim3 gt2(DD / 64, HH / 64, NEXP);
  k_wt<<<gt2, 256, 0, stream>>>(ew2, sw2, wtb, HH, DD);
  k_gemm2<<<NSG * 8 * (DD / 128), 256, 0, stream>>>(hbuf, wtb, sb2, eb2, rowTok, rowW,
                                                    expBase, expCnt, tileExp, tileM, nTiles, out);
}

// Round 5
// 859.625 us; speedup vs baseline: 1.0702x; 1.0522x over previous
//
#include <hip/hip_runtime.h>
#include <math.h>

#define TT 4096
#define DD 1024
#define EE 8
#define HH 4096
#define NEXP 9     // 8 routed experts + shared expert as index 8
#define NTMAX 104  // worst-case total m-tiles: 32 shared + 64+7 experts
#define NSG 13     // ceil(NTMAX/8) supergroups

typedef __bf16 bf16;
typedef __bf16 bf16x8 __attribute__((ext_vector_type(8)));
typedef float  f32x4  __attribute__((ext_vector_type(4)));

// async global->LDS, 16B per lane; LDS dest is wave-uniform base + lane*16
#define GLOAD_LDS16(gptr, lptr)                                                   \
  __builtin_amdgcn_global_load_lds(                                               \
      (const __attribute__((address_space(1))) void*)(gptr),                      \
      (__attribute__((address_space(3))) void*)(lptr), 16, 0, 0)

// ---------------- init: zero out + counters, convert x -> bf16 ----------------
__global__ void k_init(const float* __restrict__ x, bf16* __restrict__ xb,
                       float* __restrict__ out, int* __restrict__ counts,
                       int* __restrict__ cursors) {
  int i = blockIdx.x * blockDim.x + threadIdx.x;
  if (i < TT * DD) { xb[i] = (bf16)x[i]; out[i] = 0.0f; }
  if (i < EE) { counts[i] = 0; cursors[i] = 0; }
}

// ---------------- routing: one wave per token ----------------
__global__ void k_route(const float* __restrict__ x, const float* __restrict__ gw,
                        const float* __restrict__ gb, const float* __restrict__ rb,
                        int* __restrict__ counts, int* __restrict__ tke,
                        float* __restrict__ tkp) {
  int gid = blockIdx.x * blockDim.x + threadIdx.x;
  int t = gid >> 6;
  int lane = gid & 63;
  if (t >= TT) return;
  const float* xt = x + (size_t)t * DD;
  float acc[EE];
#pragma unroll
  for (int e = 0; e < EE; e++) acc[e] = 0.f;
  for (int d = lane; d < DD; d += 64) {
    float xv = xt[d];
    const float* g = gw + (size_t)d * EE;
#pragma unroll
    for (int e = 0; e < EE; e++) acc[e] += xv * g[e];
  }
#pragma unroll
  for (int off = 32; off > 0; off >>= 1) {
#pragma unroll
    for (int e = 0; e < EE; e++) acc[e] += __shfl_down(acc[e], off);
  }
  if (lane == 0) {
    float l[EE];
#pragma unroll
    for (int e = 0; e < EE; e++) l[e] = acc[e] + gb[e] + rb[e];
    int i1 = 0;
#pragma unroll
    for (int e = 1; e < EE; e++) if (l[e] > l[i1]) i1 = e;
    int i2 = (i1 == 0) ? 1 : 0;
#pragma unroll
    for (int e = 0; e < EE; e++) if (e != i1 && l[e] > l[i2]) i2 = e;
    float e2 = expf(l[i2] - l[i1]);
    float s = 1.f + e2;
    tke[t * 2 + 0] = i1; tkp[t * 2 + 0] = 1.f / s;
    tke[t * 2 + 1] = i2; tkp[t * 2 + 1] = e2 / s;
    atomicAdd(&counts[i1], 1);
    atomicAdd(&counts[i2], 1);
  }
}

// ---------------- prefix: expert row bases + flattened tile table ----------------
__global__ void k_prefix(const int* __restrict__ counts, int* __restrict__ expBase,
                         int* __restrict__ expCnt, int* __restrict__ tileExp,
                         int* __restrict__ tileM, int* __restrict__ nTiles) {
  if (blockIdx.x == 0 && threadIdx.x == 0) {
    int off = TT;  // rows [0, TT) are the shared expert
    for (int e = 0; e < EE; e++) { expBase[e] = off; expCnt[e] = counts[e]; off += counts[e]; }
    expBase[8] = 0; expCnt[8] = TT;
    int idx = 0;
    for (int mt = 0; mt < TT / 128; mt++) { tileExp[idx] = 8; tileM[idx] = mt; idx++; }
    for (int e = 0; e < EE; e++) {
      int nt = (counts[e] + 127) >> 7;
      for (int mt = 0; mt < nt; mt++) { tileExp[idx] = e; tileM[idx] = mt; idx++; }
    }
    *nTiles = idx;
  }
}

// ---------------- scatter: fill packed row lists ----------------
__global__ void k_scatter(const int* __restrict__ tke, const float* __restrict__ tkp,
                          const int* __restrict__ expBase, int* __restrict__ cursors,
                          int* __restrict__ rowTok, float* __restrict__ rowW) {
  int t = blockIdx.x * blockDim.x + threadIdx.x;
  if (t >= TT) return;
  rowTok[t] = t; rowW[t] = 1.f;
#pragma unroll
  for (int k = 0; k < 2; k++) {
    int e = tke[t * 2 + k];
    float p = tkp[t * 2 + k];
    int slot = atomicAdd(&cursors[e], 1);
    int r = expBase[e] + slot;
    rowTok[r] = t; rowW[r] = p;
  }
}

// ---------------- weight transpose+convert: W[K][N] fp32 -> Wt[N][K] bf16 ----------------
__global__ __launch_bounds__(256) void k_wt(const float* __restrict__ expW,
                                            const float* __restrict__ shW,
                                            bf16* __restrict__ outT, int K, int N) {
  __shared__ float t[64][65];
  int z = blockIdx.z;
  const float* W = (z == 8) ? shW : expW + (size_t)z * K * N;
  bf16* O = outT + (size_t)z * K * N;
  int n0 = blockIdx.x * 64, k0 = blockIdx.y * 64;
  int tid = threadIdx.x;
  int kr = tid >> 2;
  int cf = (tid & 3) * 16;
#pragma unroll
  for (int i = 0; i < 4; i++) {
    f32x4 v = *(const f32x4*)&W[(size_t)(k0 + kr) * N + n0 + cf + i * 4];
    t[kr][cf + i * 4 + 0] = v[0];
    t[kr][cf + i * 4 + 1] = v[1];
    t[kr][cf + i * 4 + 2] = v[2];
    t[kr][cf + i * 4 + 3] = v[3];
  }
  __syncthreads();
  int nr = tid >> 2;
  int kf = (tid & 3) * 16;
  bf16x8 o0, o1;
#pragma unroll
  for (int j = 0; j < 8; j++) o0[j] = (bf16)t[kf + j][nr];
#pragma unroll
  for (int j = 0; j < 8; j++) o1[j] = (bf16)t[kf + 8 + j][nr];
  bf16* dst = O + (size_t)(n0 + nr) * K + k0 + kf;
  *(bf16x8*)dst = o0;
  *(bf16x8*)(dst + 8) = o1;
}

// LDS chunk swizzle: k-chunk c of row r lives at position c ^ ((r>>1)&3).
// Staging source chunk for lane: (lane&3) ^ ((lane>>3)&3)  [row_local = lane>>2]
// Fragment read offset: ((lane>>4) ^ ((lane>>1)&3)) * 8    [row = .. + (lane&15)]

// ---------------- grouped GEMM1: h = gelu(X @ W1 + b1), swizzled flat grid ----------------
__global__ __launch_bounds__(256, 2) void k_gemm1(
    const bf16* __restrict__ xb, const bf16* __restrict__ wt1,
    const float* __restrict__ sb1, const float* __restrict__ eb1,
    const int* __restrict__ rowTok, const int* __restrict__ expBase,
    const int* __restrict__ expCnt, const int* __restrict__ tileExp,
    const int* __restrict__ tileM, const int* __restrict__ nTiles,
    bf16* __restrict__ hbuf) {
  int bid = blockIdx.x;
  int sg  = bid >> 8;
  int rem = bid & 255;
  int n   = rem >> 3;
  int dm  = rem & 7;
  int tIdx = sg * 8 + dm;
  if (tIdx >= *nTiles) return;
  int ex = tileExp[tIdx];
  int mt = tileM[tIdx];
  int base = expBase[ex];
  int cnt  = expCnt[ex];
  int n0 = n * 128;
  const bf16* Bt = wt1 + (size_t)ex * HH * DD;   // [H][D] bf16
  const float* b1 = (ex == 8) ? sb1 : eb1 + (size_t)ex * HH;

  __shared__ bf16 As[128 * 32];
  __shared__ bf16 Bs[128 * 32];
  __shared__ int  toks[128];

  int tid = threadIdx.x;
  int lane = tid & 63;
  int wv = tid >> 6;
  int wm = (wv & 1) * 64;
  int wn = (wv >> 1) * 64;

  if (tid < 128) {
    int rr = min(mt * 128 + tid, cnt - 1);
    toks[tid] = rowTok[base + rr];
  }

  f32x4 acc[4][4];
#pragma unroll
  for (int a = 0; a < 4; a++)
#pragma unroll
    for (int b = 0; b < 4; b++) acc[a][b] = (f32x4){0.f, 0.f, 0.f, 0.f};

  __syncthreads();

  int r0 = wv * 32 + (lane >> 2);
  int c8 = ((lane & 3) ^ ((lane >> 3) & 3)) * 8;              // swizzled source chunk
  int fsw = (((lane >> 4) ^ ((lane >> 1) & 3)) * 8);          // swizzled frag offset

  for (int k0 = 0; k0 < DD; k0 += 32) {
    GLOAD_LDS16(xb + (size_t)toks[r0] * DD + k0 + c8,      As + wv * 1024);
    GLOAD_LDS16(xb + (size_t)toks[r0 + 16] * DD + k0 + c8, As + wv * 1024 + 512);
    GLOAD_LDS16(Bt + (size_t)(n0 + r0) * DD + k0 + c8,      Bs + wv * 1024);
    GLOAD_LDS16(Bt + (size_t)(n0 + r0 + 16) * DD + k0 + c8, Bs + wv * 1024 + 512);
    __syncthreads();
    bf16x8 af[4], bfr[4];
#pragma unroll
    for (int mi = 0; mi < 4; mi++)
      af[mi] = *(const bf16x8*)&As[(wm + mi * 16 + (lane & 15)) * 32 + fsw];
#pragma unroll
    for (int ni = 0; ni < 4; ni++)
      bfr[ni] = *(const bf16x8*)&Bs[(wn + ni * 16 + (lane & 15)) * 32 + fsw];
#pragma unroll
    for (int mi = 0; mi < 4; mi++)
#pragma unroll
      for (int ni = 0; ni < 4; ni++)
        acc[mi][ni] = __builtin_amdgcn_mfma_f32_16x16x32_bf16(af[mi], bfr[ni], acc[mi][ni], 0, 0, 0);
    __syncthreads();
  }

  // -------- epilogue: cheap gelu + per-wave LDS transpose + coalesced stores --------
  // (LDS free after last barrier; wave-private 16x64 bf16 region, no cross-wave sync)
  bf16* T = ((wv & 2) ? Bs : As) + (wv & 1) * 1024;
  int colL = lane & 15;
  int rsub = (lane >> 4) * 4;
  float bs[4];
#pragma unroll
  for (int ni = 0; ni < 4; ni++) bs[ni] = b1[n0 + wn + ni * 16 + colL];
  for (int mi = 0; mi < 4; mi++) {
#pragma unroll
    for (int ni = 0; ni < 4; ni++) {
#pragma unroll
      for (int r = 0; r < 4; r++) {
        float v = acc[mi][ni][r] + bs[ni];
        float u = 1.5957691f * v * (1.f + 0.044715f * v * v);
        v = v / (1.f + __expf(-u));                      // tanh-approx gelu
        int qrow = rsub + r;
        int col = ni * 16 + colL;
        int chp = (col >> 3) ^ (qrow & 7);               // chunk xor-swizzle
        T[qrow * 64 + chp * 8 + (col & 7)] = (bf16)v;
      }
    }
    int rr = lane >> 2;
    int cb = (lane & 3) * 16;
    int ch0 = ((cb >> 3) + 0) ^ (rr & 7);
    int ch1 = ((cb >> 3) + 1) ^ (rr & 7);
    bf16x8 o0 = *(bf16x8*)&T[rr * 64 + ch0 * 8];
    bf16x8 o1 = *(bf16x8*)&T[rr * 64 + ch1 * 8];
    int mrow = mt * 128 + wm + mi * 16 + rr;
    if (mrow < cnt) {
      bf16* dst = hbuf + (size_t)(base + mrow) * HH + n0 + wn + cb;
      *(bf16x8*)dst = o0;
      *(bf16x8*)(dst + 8) = o1;
    }
  }
}

// ---------------- grouped GEMM2: out += rowW * (h @ W2 + b2), swizzled flat grid ----------------
__global__ __launch_bounds__(256, 2) void k_gemm2(
    const bf16* __restrict__ hbuf, const bf16* __restrict__ wt2,
    const float* __restrict__ sb2, const float* __restrict__ eb2,
    const int* __restrict__ rowTok, const float* __restrict__ rowW,
    const int* __restrict__ expBase, const int* __restrict__ expCnt,
    const int* __restrict__ tileExp, const int* __restrict__ tileM,
    const int* __restrict__ nTiles, float* __restrict__ out) {
  int bid = blockIdx.x;
  int sg  = bid >> 6;
  int rem = bid & 63;
  int n   = rem >> 3;
  int dm  = rem & 7;
  int tIdx = sg * 8 + dm;
  if (tIdx >= *nTiles) return;
  int ex = tileExp[tIdx];
  int mt = tileM[tIdx];
  int base = expBase[ex];
  int cnt  = expCnt[ex];
  int n0 = n * 128;
  const bf16* Bt = wt2 + (size_t)ex * DD * HH;   // [D][H] bf16
  const float* b2 = (ex == 8) ? sb2 : eb2 + (size_t)ex * DD;

  __shared__ bf16 As[128 * 32];
  __shared__ bf16 Bs[128 * 32];
  __shared__ int   toks[128];
  __shared__ float wrow[128];

  int tid = threadIdx.x;
  int lane = tid & 63;
  int wv = tid >> 6;
  int wm = (wv & 1) * 64;
  int wn = (wv >> 1) * 64;

  if (tid < 128) {
    int rr = min(mt * 128 + tid, cnt - 1);
    toks[tid] = rowTok[base + rr];
    wrow[tid] = rowW[base + rr];
  }

  f32x4 acc[4][4];
#pragma unroll
  for (int a = 0; a < 4; a++)
#pragma unroll
    for (int b = 0; b < 4; b++) acc[a][b] = (f32x4){0.f, 0.f, 0.f, 0.f};

  __syncthreads();

  int r0 = wv * 32 + (lane >> 2);
  int c8 = ((lane & 3) ^ ((lane >> 3) & 3)) * 8;
  int fsw = (((lane >> 4) ^ ((lane >> 1) & 3)) * 8);
  int pr0 = base + min(mt * 128 + r0, cnt - 1);
  int pr1 = base + min(mt * 128 + r0 + 16, cnt - 1);
  const bf16* ga0 = hbuf + (size_t)pr0 * HH + c8;
  const bf16* ga1 = hbuf + (size_t)pr1 * HH + c8;

  for (int k0 = 0; k0 < HH; k0 += 32) {
    GLOAD_LDS16(ga0 + k0, As + wv * 1024);
    GLOAD_LDS16(ga1 + k0, As + wv * 1024 + 512);
    GLOAD_LDS16(Bt + (size_t)(n0 + r0) * HH + k0 + c8,      Bs + wv * 1024);
    GLOAD_LDS16(Bt + (size_t)(n0 + r0 + 16) * HH + k0 + c8, Bs + wv * 1024 + 512);
    __syncthreads();
    bf16x8 af[4], bfr[4];
#pragma unroll
    for (int mi = 0; mi < 4; mi++)
      af[mi] = *(const bf16x8*)&As[(wm + mi * 16 + (lane & 15)) * 32 + fsw];
#pragma unroll
    for (int ni = 0; ni < 4; ni++)
      bfr[ni] = *(const bf16x8*)&Bs[(wn + ni * 16 + (lane & 15)) * 32 + fsw];
#pragma unroll
    for (int mi = 0; mi < 4; mi++)
#pragma unroll
      for (int ni = 0; ni < 4; ni++)
        acc[mi][ni] = __builtin_amdgcn_mfma_f32_16x16x32_bf16(af[mi], bfr[ni], acc[mi][ni], 0, 0, 0);
    __syncthreads();
  }

  int rsub = (lane >> 4) * 4;
#pragma unroll
  for (int ni = 0; ni < 4; ni++) {
    int col = n0 + wn + ni * 16 + (lane & 15);
    float bias = b2[col];
#pragma unroll
    for (int mi = 0; mi < 4; mi++) {
#pragma unroll
      for (int r = 0; r < 4; r++) {
        int local = wm + mi * 16 + rsub + r;
        int mrow = mt * 128 + local;
        if (mrow < cnt) {
          float v = acc[mi][ni][r] + bias;
          atomicAdd(&out[(size_t)toks[local] * DD + col], wrow[local] * v);
        }
      }
    }
  }
}

extern "C" void kernel_launch(void* const* d_in, const int* in_sizes, int n_in,
                              void* d_out, int out_size, void* d_ws, size_t ws_size,
                              hipStream_t stream) {
  const float* x   = (const float*)d_in[0];
  const float* gw  = (const float*)d_in[1];
  const float* gb  = (const float*)d_in[2];
  const float* rb  = (const float*)d_in[3];
  const float* sw1 = (const float*)d_in[4];
  const float* sb1 = (const float*)d_in[5];
  const float* sw2 = (const float*)d_in[6];
  const float* sb2 = (const float*)d_in[7];
  const float* ew1 = (const float*)d_in[8];
  const float* eb1 = (const float*)d_in[9];
  const float* ew2 = (const float*)d_in[10];
  const float* eb2 = (const float*)d_in[11];
  float* out = (float*)d_out;

  char* p = (char*)d_ws;
  bf16* xb    = (bf16*)p;  p += (size_t)TT * DD * sizeof(bf16);          // 8 MB
  bf16* hbuf  = (bf16*)p;  p += (size_t)(3 * TT) * HH * sizeof(bf16);    // 96 MB
  bf16* wtb   = (bf16*)p;  p += (size_t)NEXP * DD * HH * sizeof(bf16);   // 75.5 MB (W1^T, then W2^T)
  int* rowTok = (int*)p;   p += (size_t)(3 * TT) * sizeof(int);
  float* rowW = (float*)p; p += (size_t)(3 * TT) * sizeof(float);
  int* tke    = (int*)p;   p += (size_t)TT * 2 * sizeof(int);
  float* tkp  = (float*)p; p += (size_t)TT * 2 * sizeof(float);
  int* counts = (int*)p;   p += EE * sizeof(int);
  int* cursors= (int*)p;   p += EE * sizeof(int);
  int* expBase= (int*)p;   p += NEXP * sizeof(int);
  int* expCnt = (int*)p;   p += NEXP * sizeof(int);
  int* tileExp= (int*)p;   p += 128 * sizeof(int);
  int* tileM  = (int*)p;   p += 128 * sizeof(int);
  int* nTiles = (int*)p;   p += 8 * sizeof(int);

  k_init<<<(TT * DD + 255) / 256, 256, 0, stream>>>(x, xb, out, counts, cursors);
  k_route<<<TT / 4, 256, 0, stream>>>(x, gw, gb, rb, counts, tke, tkp);
  k_prefix<<<1, 64, 0, stream>>>(counts, expBase, expCnt, tileExp, tileM, nTiles);
  k_scatter<<<TT / 256, 256, 0, stream>>>(tke, tkp, expBase, cursors, rowTok, rowW);

  // W1^T: [DD][HH] fp32 -> [HH][DD] bf16
  dim3 gt1(HH / 64, DD / 64, NEXP);
  k_wt<<<gt1, 256, 0, stream>>>(ew1, sw1, wtb, DD, HH);
  k_gemm1<<<NSG * 8 * (HH / 128), 256, 0, stream>>>(xb, wtb, sb1, eb1, rowTok, expBase,
                                                    expCnt, tileExp, tileM, nTiles, hbuf);

  // W2^T: [HH][DD] fp32 -> [DD][HH] bf16 (overwrites W1^T)
  dim3 gt2(DD / 64, HH / 64, NEXP);
  k_wt<<<gt2, 256, 0, stream>>>(ew2, sw2, wtb, HH, DD);
  k_gemm2<<<NSG * 8 * (DD / 128), 256, 0, stream>>>(hbuf, wtb, sb2, eb2, rowTok, rowW,
                                                    expBase, expCnt, tileExp, tileM, nTiles, out);
}